// Round 6
// baseline (993.024 us; speedup 1.0000x reference)
//
#include <hip/hip_runtime.h>
#include <hip/hip_bf16.h>

typedef __bf16 bf16x8 __attribute__((ext_vector_type(8)));
typedef float  f32x4  __attribute__((ext_vector_type(4)));

#define MFMA16(a,b,c) __builtin_amdgcn_mfma_f32_16x16x32_bf16((a),(b),(c),0,0,0)

__device__ __forceinline__ bf16x8 cvt8(f32x4 a, f32x4 b){
  bf16x8 r;
  r[0]=(__bf16)a[0]; r[1]=(__bf16)a[1]; r[2]=(__bf16)a[2]; r[3]=(__bf16)a[3];
  r[4]=(__bf16)b[0]; r[5]=(__bf16)b[1]; r[6]=(__bf16)b[2]; r[7]=(__bf16)b[3];
  return r;
}
__device__ __forceinline__ bf16x8 ld8(const float* p){
  return cvt8(*(const f32x4*)p, *(const f32x4*)(p+4));
}
__device__ __forceinline__ float sigm(float x){
  return __builtin_amdgcn_rcpf(1.f + __expf(-x));
}
__device__ __forceinline__ float tanhx(float x){
  return 1.f - 2.f*__builtin_amdgcn_rcpf(1.f + __expf(2.f*x));
}
__device__ __forceinline__ f32x4 sp(float v){ return (f32x4){v,v,v,v}; }

extern "C" __global__ void __launch_bounds__(512, 2)   // 8 waves, 2/SIMD, 256 regs/wave
seq2seq_kernel(const float* __restrict__ X,
               const float* __restrict__ Wemb, const float* __restrict__ bemb,
               const float* __restrict__ eWih, const float* __restrict__ eWhh,
               const float* __restrict__ ebih, const float* __restrict__ ebhh,
               const float* __restrict__ dWih, const float* __restrict__ dWhh,
               const float* __restrict__ dbih, const float* __restrict__ dbhh,
               const float* __restrict__ Wreg, const float* __restrict__ breg,
               float* __restrict__ out)
{
  // Two wave-groups (waves 0-3 / 4-7), each owns 4 batch rows and runs one
  // phase out of step with the other -> on every SIMD, one wave does MFMA
  // while its partner does VALU/trans (deterministic co-issue).
  // XA[g][parity][4 rows][208]: cols 0..63=x, 64..127=h0, 128..191=h1.
  // Row stride 104 dw == 8 mod 32; G stride 264 dw == 8 mod 32 -> all LDS <=2-way.
  __shared__ __align__(16) __bf16 XA[2][2][4][208];
  __shared__ __align__(16) float  Gm[2][2][4][264];

  const int tid  = (int)threadIdx.x;
  const int w    = tid >> 6;
  const bool grpA = (w < 4);
  const int grp  = w >> 2;            // 0 / 1
  const int wt   = w & 3;             // wave-in-group; also this lane's batch row
  const int lane = tid & 63;
  const int col  = lane & 15;
  const int quad = lane >> 4;
  const int row4 = col & 3;           // A-matrix real row (M=16 mirrors 4 rows)
  const int b0   = (int)blockIdx.x * 8;
  const int brow = b0 + grp*4 + row4;

  const int ue = wt*16 + col;         // emb unit owned by this lane
  const int nq = 64*wt + 16*quad + col;  // G column this lane stores (tile=quad)

#define AFR(P,BASE,KS) (*(const bf16x8*)&XA[grp][P][row4][(BASE) + (KS)*32 + quad*8])

  for (int idx = tid; idx < 2*2*4*208; idx += 512)
    (&XA[0][0][0][0])[idx] = (__bf16)0.f;

  // ---- persistent fragments ----
  bf16x8 wembf = ld8(Wemb + ue*32 + quad*8);
  const float eb = bemb[ue];

  bf16x8 wr[2];
#pragma unroll
  for (int ks=0; ks<2; ++ks) wr[ks] = ld8(Wreg + (col&7)*64 + ks*32 + quad*8);
  const float rb = breg[col&7];

  // wave covers gate cols [64*wt, 64*wt+63]: 4 tiles x 2 layers x 4 ksteps
  bf16x8 wf[2][4][4];
  float  gbias[2][4];
#pragma unroll
  for (int l=0; l<2; ++l)
#pragma unroll
    for (int j=0; j<4; ++j){
      const int n = 64*wt + 16*j + col;
      gbias[l][j] = ebih[l*256+n] + ebhh[l*256+n];
#pragma unroll
      for (int ks=0; ks<4; ++ks){
        const float* srcw = (ks < 2) ? eWih : eWhh;
        wf[l][j][ks] = ld8(srcw + ((size_t)(l*256+n))*64 + (ks&1)*32 + quad*8);
      }
    }

  float c0 = 0.f, c1 = 0.f;
  const float* xb = X + (size_t)brow*512*32 + quad*8;
  f32x4 pa[2], pb[2];

  // gates GEMM for both layers (pipelined: L1(i) and L0(i+1) inputs), + emb(i+2)
  auto GEMM_ENC = [&](int i, int P){
    bf16x8 ax0 = AFR(P,  0,0), ax1 = AFR(P,  0,1);
    bf16x8 ah0 = AFR(P, 64,0), ah1 = AFR(P, 64,1);
    bf16x8 ag0 = AFR(P,128,0), ag1 = AFR(P,128,1);
    f32x4 A0[4], A1[4];
#pragma unroll
    for (int j=0;j<4;++j){ A0[j]=sp(gbias[0][j]); A1[j]=sp(gbias[1][j]); }
#pragma unroll
    for (int j=0;j<4;++j){
      A0[j]=MFMA16(ax0,wf[0][j][0],A0[j]);  A1[j]=MFMA16(ah0,wf[1][j][0],A1[j]);
      A0[j]=MFMA16(ax1,wf[0][j][1],A0[j]);  A1[j]=MFMA16(ah1,wf[1][j][1],A1[j]);
      A0[j]=MFMA16(ah0,wf[0][j][2],A0[j]);  A1[j]=MFMA16(ag0,wf[1][j][2],A1[j]);
      A0[j]=MFMA16(ah1,wf[0][j][3],A0[j]);  A1[j]=MFMA16(ag1,wf[1][j][3],A1[j]);
    }
    const int s = i&1;
    f32x4 ea = MFMA16(cvt8(pa[s],pb[s]), wembf, sp(eb));
    int tn = i+4; if (tn>511) tn=511;
    pa[s] = *(const f32x4*)(xb + (size_t)tn*32);
    pb[s] = *(const f32x4*)(xb + (size_t)tn*32 + 4);
    // store: quad q stores tile q (each quad holds a full 4-row copy)
    f32x4 u0=(quad&1)?A0[1]:A0[0], u1=(quad&1)?A0[3]:A0[2];
    f32x4 t0=(quad&2)?u1:u0;
    f32x4 v0=(quad&1)?A1[1]:A1[0], v1=(quad&1)?A1[3]:A1[2];
    f32x4 t1=(quad&2)?v1:v0;
#pragma unroll
    for (int r=0;r<4;++r){ Gm[grp][0][r][nq]=t0[r]; Gm[grp][1][r][nq]=t1[r]; }
    if (quad==0){
#pragma unroll
      for (int r=0;r<4;++r) XA[grp][P^1][r][ue] = (__bf16)ea[r];
    }
  };

  auto GEMM_L1 = [&](int P){     // L1-only gates (encoder epilogue)
    bf16x8 ah0 = AFR(P, 64,0), ah1 = AFR(P, 64,1);
    bf16x8 ag0 = AFR(P,128,0), ag1 = AFR(P,128,1);
    f32x4 A1[4];
#pragma unroll
    for (int j=0;j<4;++j) A1[j]=sp(gbias[1][j]);
#pragma unroll
    for (int j=0;j<4;++j){
      A1[j]=MFMA16(ah0,wf[1][j][0],A1[j]);
      A1[j]=MFMA16(ah1,wf[1][j][1],A1[j]);
      A1[j]=MFMA16(ag0,wf[1][j][2],A1[j]);
      A1[j]=MFMA16(ag1,wf[1][j][3],A1[j]);
    }
    f32x4 v0=(quad&1)?A1[1]:A1[0], v1=(quad&1)?A1[3]:A1[2];
    f32x4 t1=(quad&2)?v1:v0;
#pragma unroll
    for (int r=0;r<4;++r) Gm[grp][1][r][nq]=t1[r];
  };

  auto EW_ENC = [&](int qw){     // both layers' elementwise; writes h into parity qw
    const float* g0p = Gm[grp][0][wt];
    const float* g1p = Gm[grp][1][wt];
    float i0=sigm(g0p[lane]),     i1=sigm(g1p[lane]);
    float f0=sigm(g0p[64+lane]),  f1=sigm(g1p[64+lane]);
    float gg0=tanhx(g0p[128+lane]), gg1=tanhx(g1p[128+lane]);
    float o0=sigm(g0p[192+lane]), o1=sigm(g1p[192+lane]);
    c0 = f0*c0 + i0*gg0;
    c1 = f1*c1 + i1*gg1;
    XA[grp][qw][wt][64+lane]  = (__bf16)(o0*tanhx(c0));
    XA[grp][qw][wt][128+lane] = (__bf16)(o1*tanhx(c1));
  };

  auto EW_L1 = [&](int qw){
    const float* g1p = Gm[grp][1][wt];
    float i1=sigm(g1p[lane]);
    float f1=sigm(g1p[64+lane]);
    float gg1=tanhx(g1p[128+lane]);
    float o1=sigm(g1p[192+lane]);
    c1 = f1*c1 + i1*gg1;
    XA[grp][qw][wt][128+lane] = (__bf16)(o1*tanhx(c1));
  };

  __syncthreads();                       // zero-init visible

  // ---- prologue (both groups in lockstep) ----
  {
    f32x4 x0a = *(const f32x4*)(xb),    x0b = *(const f32x4*)(xb+4);
    pa[1] = *(const f32x4*)(xb+96);  pb[1] = *(const f32x4*)(xb+100);
    pa[0] = *(const f32x4*)(xb+64);  pb[0] = *(const f32x4*)(xb+68);
    f32x4 x1a = *(const f32x4*)(xb+32), x1b = *(const f32x4*)(xb+36);
    f32x4 e0 = MFMA16(cvt8(x0a,x0b), wembf, sp(eb));
    if (quad==0){
#pragma unroll
      for (int r=0;r<4;++r) XA[grp][0][r][ue] = (__bf16)e0[r];
    }
    __syncthreads();
    { // preG: L0(0) gates (h0 cols are zero)
      bf16x8 ax0 = AFR(0,0,0), ax1 = AFR(0,0,1);
      bf16x8 ah0 = AFR(0,64,0), ah1 = AFR(0,64,1);
      f32x4 A0[4];
#pragma unroll
      for (int j=0;j<4;++j) A0[j]=sp(gbias[0][j]);
#pragma unroll
      for (int j=0;j<4;++j){
        A0[j]=MFMA16(ax0,wf[0][j][0],A0[j]);
        A0[j]=MFMA16(ax1,wf[0][j][1],A0[j]);
        A0[j]=MFMA16(ah0,wf[0][j][2],A0[j]);
        A0[j]=MFMA16(ah1,wf[0][j][3],A0[j]);
      }
      f32x4 u0=(quad&1)?A0[1]:A0[0], u1=(quad&1)?A0[3]:A0[2];
      f32x4 t0=(quad&2)?u1:u0;
#pragma unroll
      for (int r=0;r<4;++r) Gm[grp][0][r][nq]=t0[r];
    }
    __syncthreads();
    { // preE: h0(0) -> XA[0].h0, emb(1) -> XA[0].x
      const float* g0p = Gm[grp][0][wt];
      float i0=sigm(g0p[lane]), f0=sigm(g0p[64+lane]);
      float gg0=tanhx(g0p[128+lane]), o0=sigm(g0p[192+lane]);
      c0 = f0*c0 + i0*gg0;
      XA[grp][0][wt][64+lane] = (__bf16)(o0*tanhx(c0));
      f32x4 e1 = MFMA16(cvt8(x1a,x1b), wembf, sp(eb));
      if (quad==0){
#pragma unroll
        for (int r=0;r<4;++r) XA[grp][0][r][ue] = (__bf16)e1[r];
      }
    }
    __syncthreads();
  }

  // ---- steady encoder: group B lags group A by one phase ----
  for (int i=0; i<510; i+=2){
    if (grpA) GEMM_ENC(i,0);   else { if (i>0) EW_ENC(0); }
    __syncthreads();
    if (grpA) EW_ENC(1);       else GEMM_ENC(i,0);
    __syncthreads();
    if (grpA) GEMM_ENC(i+1,1); else EW_ENC(1);
    __syncthreads();
    if (grpA) EW_ENC(0);       else GEMM_ENC(i+1,1);
    __syncthreads();
  }
  // i = 510 (P=0) + L1(511) epilogue
  if (grpA) GEMM_ENC(510,0); else EW_ENC(0);
  __syncthreads();
  if (grpA) EW_ENC(1);       else GEMM_ENC(510,0);
  __syncthreads();
  if (grpA) GEMM_L1(1);      else EW_ENC(1);
  __syncthreads();
  if (grpA) EW_L1(1);        else GEMM_L1(1);
  __syncthreads();
  if (!grpA) EW_L1(1);
  __syncthreads();

  // ---- decoder init: XA[g][0] = [x=h1 | h0 | h1] from XA[g][1]; c=0 ----
  for (int idx = tid; idx < 2*4*192; idx += 512){
    int g2 = idx/768, rem = idx%768, r = rem/192, cc = rem%192;
    __bf16 v = (cc < 64) ? XA[g2][1][r][128+cc] : XA[g2][1][r][cc];
    XA[g2][0][r][cc] = v;
  }
#pragma unroll
  for (int l=0; l<2; ++l)
#pragma unroll
    for (int j=0; j<4; ++j){
      const int n = 64*wt + 16*j + col;
      gbias[l][j] = dbih[l*256+n] + dbhh[l*256+n];
#pragma unroll
      for (int ks=0; ks<4; ++ks){
        const float* srcw = (ks < 2) ? dWih : dWhh;
        wf[l][j][ks] = ld8(srcw + ((size_t)(l*256+n))*64 + (ks&1)*32 + quad*8);
      }
    }
  c0 = 0.f; c1 = 0.f;
  __syncthreads();

  // ---- decoder bodies (single buffer XA[g][0]) ----
#define AFRD(BASE,KS) (*(const bf16x8*)&XA[grp][0][row4][(BASE) + (KS)*32 + quad*8])
  auto G0f = [&]{
    bf16x8 ax0 = AFRD(0,0), ax1 = AFRD(0,1);
    bf16x8 ah0 = AFRD(64,0), ah1 = AFRD(64,1);
    f32x4 A0[4];
#pragma unroll
    for (int j=0;j<4;++j) A0[j]=sp(gbias[0][j]);
#pragma unroll
    for (int j=0;j<4;++j){
      A0[j]=MFMA16(ax0,wf[0][j][0],A0[j]);
      A0[j]=MFMA16(ax1,wf[0][j][1],A0[j]);
      A0[j]=MFMA16(ah0,wf[0][j][2],A0[j]);
      A0[j]=MFMA16(ah1,wf[0][j][3],A0[j]);
    }
    f32x4 u0=(quad&1)?A0[1]:A0[0], u1=(quad&1)?A0[3]:A0[2];
    f32x4 t0=(quad&2)?u1:u0;
#pragma unroll
    for (int r=0;r<4;++r) Gm[grp][0][r][nq]=t0[r];
  };
  auto G1f = [&]{
    bf16x8 ah0 = AFRD(64,0), ah1 = AFRD(64,1);
    bf16x8 ag0 = AFRD(128,0), ag1 = AFRD(128,1);
    f32x4 A1[4];
#pragma unroll
    for (int j=0;j<4;++j) A1[j]=sp(gbias[1][j]);
#pragma unroll
    for (int j=0;j<4;++j){
      A1[j]=MFMA16(ah0,wf[1][j][0],A1[j]);
      A1[j]=MFMA16(ah1,wf[1][j][1],A1[j]);
      A1[j]=MFMA16(ag0,wf[1][j][2],A1[j]);
      A1[j]=MFMA16(ag1,wf[1][j][3],A1[j]);
    }
    f32x4 v0=(quad&1)?A1[1]:A1[0], v1=(quad&1)?A1[3]:A1[2];
    f32x4 t1=(quad&2)?v1:v0;
#pragma unroll
    for (int r=0;r<4;++r) Gm[grp][1][r][nq]=t1[r];
  };
  auto E0f = [&]{
    const float* g0p = Gm[grp][0][wt];
    float i0=sigm(g0p[lane]), f0=sigm(g0p[64+lane]);
    float gg0=tanhx(g0p[128+lane]), o0=sigm(g0p[192+lane]);
    c0 = f0*c0 + i0*gg0;
    XA[grp][0][wt][64+lane] = (__bf16)(o0*tanhx(c0));
  };
  auto E1f = [&]{
    const float* g1p = Gm[grp][1][wt];
    float i1=sigm(g1p[lane]), f1=sigm(g1p[64+lane]);
    float gg1=tanhx(g1p[128+lane]), o1=sigm(g1p[192+lane]);
    c1 = f1*c1 + i1*gg1;
    __bf16 hb = (__bf16)(o1*tanhx(c1));
    XA[grp][0][wt][128+lane] = hb;
    XA[grp][0][wt][lane]     = hb;       // feedback -> next L0 input
  };
  auto Ystore = [&](int t){
    if (wt==0){
      f32x4 ya = sp(rb);
#pragma unroll
      for (int ks=0;ks<2;++ks){
        bf16x8 ah = *(const bf16x8*)&XA[grp][0][row4][128 + ks*32 + quad*8];
        ya = MFMA16(ah, wr[ks], ya);
      }
      if (quad==0 && col<8){
#pragma unroll
        for (int r=0;r<4;++r)
          out[((size_t)(b0 + grp*4 + r)*48 + t)*8 + col] = ya[r];
      }
    }
  };

  // ---- decoder: 4 phases/t, group B lags by one phase; y folded into next G0 phase ----
  for (int t=0; t<48; ++t){
    if (grpA){ G0f(); if (t) Ystore(t-1); } else { if (t) E1f(); }
    __syncthreads();
    if (grpA) E0f(); else { G0f(); if (t) Ystore(t-1); }
    __syncthreads();
    if (grpA) G1f(); else E0f();
    __syncthreads();
    if (grpA) E1f(); else G1f();
    __syncthreads();
  }
  if (grpA) Ystore(47); else E1f();
  __syncthreads();
  if (!grpA) Ystore(47);
#undef AFRD
#undef AFR
}

extern "C" void kernel_launch(void* const* d_in, const int* in_sizes, int n_in,
                              void* d_out, int out_size, void* d_ws, size_t ws_size,
                              hipStream_t stream)
{
  (void)in_sizes; (void)n_in; (void)out_size; (void)d_ws; (void)ws_size;
  const float* X    = (const float*)d_in[0];
  const float* Wemb = (const float*)d_in[2];
  const float* bemb = (const float*)d_in[3];
  const float* eWih = (const float*)d_in[4];
  const float* eWhh = (const float*)d_in[5];
  const float* ebih = (const float*)d_in[6];
  const float* ebhh = (const float*)d_in[7];
  const float* dWih = (const float*)d_in[8];
  const float* dWhh = (const float*)d_in[9];
  const float* dbih = (const float*)d_in[10];
  const float* dbhh = (const float*)d_in[11];
  const float* Wreg = (const float*)d_in[12];
  const float* breg = (const float*)d_in[13];
  float* out = (float*)d_out;

  seq2seq_kernel<<<dim3(256), dim3(512), 0, stream>>>(
      X, Wemb, bemb, eWih, eWhh, ebih, ebhh,
      dWih, dWhh, dbih, dbhh, Wreg, breg, out);
}

// Round 7
// 651.576 us; speedup vs baseline: 1.5240x; 1.5240x over previous
//
#include <hip/hip_runtime.h>
#include <hip/hip_bf16.h>

typedef __bf16 bf16x8 __attribute__((ext_vector_type(8)));
typedef float  f32x4  __attribute__((ext_vector_type(4)));

#define MFMA16(a,b,c) __builtin_amdgcn_mfma_f32_16x16x32_bf16((a),(b),(c),0,0,0)

__device__ __forceinline__ bf16x8 cvt8(f32x4 a, f32x4 b){
  bf16x8 r;
  r[0]=(__bf16)a[0]; r[1]=(__bf16)a[1]; r[2]=(__bf16)a[2]; r[3]=(__bf16)a[3];
  r[4]=(__bf16)b[0]; r[5]=(__bf16)b[1]; r[6]=(__bf16)b[2]; r[7]=(__bf16)b[3];
  return r;
}
__device__ __forceinline__ bf16x8 ld8(const float* p){
  return cvt8(*(const f32x4*)p, *(const f32x4*)(p+4));
}
__device__ __forceinline__ float sigm(float x){
  return __builtin_amdgcn_rcpf(1.f + __expf(-x));
}
__device__ __forceinline__ float tanhx(float x){
  return 1.f - 2.f*__builtin_amdgcn_rcpf(1.f + __expf(2.f*x));
}
__device__ __forceinline__ f32x4 sp(float v){ return (f32x4){v,v,v,v}; }

// Layer-split co-issue: waves 0-3 own layer0 (GEMM+EW), waves 4-7 own layer1,
// running in anti-phase -> each SIMD co-issues one MFMA wave + one trans wave.
extern "C" __global__ void __launch_bounds__(512, 1)
seq2seq_kernel(const float* __restrict__ X,
               const float* __restrict__ Wemb, const float* __restrict__ bemb,
               const float* __restrict__ eWih, const float* __restrict__ eWhh,
               const float* __restrict__ ebih, const float* __restrict__ ebhh,
               const float* __restrict__ dWih, const float* __restrict__ dWhh,
               const float* __restrict__ dbih, const float* __restrict__ dbhh,
               const float* __restrict__ Wreg, const float* __restrict__ breg,
               float* __restrict__ out)
{
  // XA[parity][row][136]: cols 0-63 = x/input, 64-127 = h0. Stride 136 bf16 =
  // 68 dw == 4 mod 32 (rows 0..7 spread over all banks). H1 stride 36 dw == 4.
  // Gm stride 260 dw == 4: quad-select store pattern is 2-way max (free).
  __shared__ __align__(16) __bf16 XA[2][8][136];
  __shared__ __align__(16) __bf16 H1s[8][72];
  __shared__ __align__(16) float  Gm[2][8][260];

  const int tid  = (int)threadIdx.x;
  const int w    = tid >> 6;
  const int grp  = w >> 2;           // 0: layer-0 group, 1: layer-1 group
  const bool g0  = (grp == 0);
  const int wt   = w & 3;
  const int lane = tid & 63;
  const int col  = lane & 15;
  const int quad = lane >> 4;
  const int row8 = col & 7;          // A real row (M=16 mirrors 8 rows)
  const int b0   = (int)blockIdx.x * 8;
  const int brow = b0 + row8;

  for (int i = tid; i < 2*8*136; i += 512) (&XA[0][0][0])[i] = (__bf16)0.f;
  for (int i = tid; i < 8*72;    i += 512) (&H1s[0][0])[i]   = (__bf16)0.f;

  // ---- persistent fragments (per-wave live set ~160 regs, fits 256 cap) ----
  const int ue = wt*16 + col;                    // emb unit (grp0)
  bf16x8 wembf = ld8(Wemb + ue*32 + quad*8);
  const float eb = bemb[ue];

  bf16x8 wr[2];
#pragma unroll
  for (int ks=0; ks<2; ++ks) wr[ks] = ld8(Wreg + (col&7)*64 + ks*32 + quad*8);
  const float rb = breg[col&7];

  // Encoder weights: layer = grp, wave covers gate cols [64*wt, 64*wt+63]
  // (4 tiles). 4 tiles x 4 ksteps x 4 VGPR = 64 regs.
  bf16x8 wf[16];
  float  gb[4];
#pragma unroll
  for (int j=0; j<4; ++j){
    const int n = 64*wt + 16*j + col;
    gb[j] = ebih[grp*256+n] + ebhh[grp*256+n];
#pragma unroll
    for (int ks=0; ks<4; ++ks){
      const float* srcw = (ks < 2) ? eWih : eWhh;
      wf[j*4+ks] = ld8(srcw + ((size_t)(grp*256+n))*64 + (ks&1)*32 + quad*8);
    }
  }

  float cA = 0.f, cB = 0.f;   // grp0: c0 of rows wt/wt+4; grp1: c1 of rows wt/wt+4
  const float* xb = X + (size_t)brow*512*32 + quad*8;
  f32x4 pa0, pb0, pa1, pb1;
  f32x4 x0a = *(const f32x4*)xb, x0b = *(const f32x4*)(xb+4);
  pa1 = *(const f32x4*)(xb+32); pb1 = *(const f32x4*)(xb+36);   // x(1)
  pa0 = *(const f32x4*)(xb+64); pb0 = *(const f32x4*)(xb+68);   // x(2)

  // grp0: gates of L0(I+1) -> Gm[0]; also emb(I+2) -> XA[I&1].x
  auto GEMM0 = [&](const int I){
    const int Px = (I+1)&1, Pr = I&1;
    bf16x8 ax0 = *(const bf16x8*)&XA[Px][row8][ 0 + quad*8];
    bf16x8 ax1 = *(const bf16x8*)&XA[Px][row8][32 + quad*8];
    bf16x8 ah0 = *(const bf16x8*)&XA[Pr][row8][64 + quad*8];
    bf16x8 ah1 = *(const bf16x8*)&XA[Pr][row8][96 + quad*8];
    f32x4 A0=sp(gb[0]), A1=sp(gb[1]), A2=sp(gb[2]), A3=sp(gb[3]);
    A0=MFMA16(ax0,wf[0],A0);  A1=MFMA16(ax0,wf[4],A1);
    A2=MFMA16(ax0,wf[8],A2);  A3=MFMA16(ax0,wf[12],A3);
    A0=MFMA16(ax1,wf[1],A0);  A1=MFMA16(ax1,wf[5],A1);
    A2=MFMA16(ax1,wf[9],A2);  A3=MFMA16(ax1,wf[13],A3);
    A0=MFMA16(ah0,wf[2],A0);  A1=MFMA16(ah0,wf[6],A1);
    A2=MFMA16(ah0,wf[10],A2); A3=MFMA16(ah0,wf[14],A3);
    A0=MFMA16(ah1,wf[3],A0);  A1=MFMA16(ah1,wf[7],A1);
    A2=MFMA16(ah1,wf[11],A2); A3=MFMA16(ah1,wf[15],A3);
    if (I < 510){
      const int s = I&1;                       // call sites fold this
      f32x4 xr0 = s ? pa1 : pa0, xr1 = s ? pb1 : pb0;
      f32x4 ea = MFMA16(cvt8(xr0,xr1), wembf, sp(eb));
      int tn = I+4; if (tn > 511) tn = 511;
      f32x4 na = *(const f32x4*)(xb + (size_t)tn*32);
      f32x4 nb = *(const f32x4*)(xb + (size_t)tn*32 + 4);
      if (s){ pa1=na; pb1=nb; } else { pa0=na; pb0=nb; }
      if (quad < 2){
#pragma unroll
        for (int r=0; r<4; ++r) XA[s][quad*4+r][ue] = (__bf16)ea[r];
      }
    }
    // quad-select store: q0/q1 -> tiles 0,1 rows 0-3/4-7; q2/q3 -> tiles 2,3
    f32x4 t0 = (quad&2) ? A2 : A0;
    f32x4 t1 = (quad&2) ? A3 : A1;
    const int rb2 = (quad&1)*4;
    const int nn  = 64*wt + ((quad&2)?32:0) + col;
#pragma unroll
    for (int r=0; r<4; ++r){ Gm[0][rb2+r][nn] = t0[r]; Gm[0][rb2+r][nn+16] = t1[r]; }
  };

  // grp1: gates of L1(I) = [h0(I) | h1(I-1)] -> Gm[1]
  auto GEMM1 = [&](const int I){
    const int Pr = I&1;
    bf16x8 ah0 = *(const bf16x8*)&XA[Pr][row8][64 + quad*8];
    bf16x8 ah1 = *(const bf16x8*)&XA[Pr][row8][96 + quad*8];
    bf16x8 ag0 = *(const bf16x8*)&H1s[row8][quad*8];
    bf16x8 ag1 = *(const bf16x8*)&H1s[row8][32 + quad*8];
    f32x4 A0=sp(gb[0]), A1=sp(gb[1]), A2=sp(gb[2]), A3=sp(gb[3]);
    A0=MFMA16(ah0,wf[0],A0);  A1=MFMA16(ah0,wf[4],A1);
    A2=MFMA16(ah0,wf[8],A2);  A3=MFMA16(ah0,wf[12],A3);
    A0=MFMA16(ah1,wf[1],A0);  A1=MFMA16(ah1,wf[5],A1);
    A2=MFMA16(ah1,wf[9],A2);  A3=MFMA16(ah1,wf[13],A3);
    A0=MFMA16(ag0,wf[2],A0);  A1=MFMA16(ag0,wf[6],A1);
    A2=MFMA16(ag0,wf[10],A2); A3=MFMA16(ag0,wf[14],A3);
    A0=MFMA16(ag1,wf[3],A0);  A1=MFMA16(ag1,wf[7],A1);
    A2=MFMA16(ag1,wf[11],A2); A3=MFMA16(ag1,wf[15],A3);
    f32x4 t0 = (quad&2) ? A2 : A0;
    f32x4 t1 = (quad&2) ? A3 : A1;
    const int rb2 = (quad&1)*4;
    const int nn  = 64*wt + ((quad&2)?32:0) + col;
#pragma unroll
    for (int r=0; r<4; ++r){ Gm[1][rb2+r][nn] = t0[r]; Gm[1][rb2+r][nn+16] = t1[r]; }
  };

  // grp0 EW: 2 cells/lane (rows wt, wt+4; unit=lane) -> h0(I+1), parity (I+1)&1
  auto EW0 = [&](const int I){
    const int Pw = (I+1)&1;
    const float* ga = Gm[0][wt];
    const float* gc = Gm[0][wt+4];
    float iA=sigm(ga[lane]),    iB=sigm(gc[lane]);
    float fA=sigm(ga[64+lane]), fB=sigm(gc[64+lane]);
    float gA=tanhx(ga[128+lane]), gB=tanhx(gc[128+lane]);
    float oA=sigm(ga[192+lane]),  oB=sigm(gc[192+lane]);
    cA = fA*cA + iA*gA;
    cB = fB*cB + iB*gB;
    XA[Pw][wt  ][64+lane] = (__bf16)(oA*tanhx(cA));
    XA[Pw][wt+4][64+lane] = (__bf16)(oB*tanhx(cB));
  };

  // grp1 EW -> h1 (single buffer)
  auto EW1 = [&](){
    const float* ga = Gm[1][wt];
    const float* gc = Gm[1][wt+4];
    float iA=sigm(ga[lane]),    iB=sigm(gc[lane]);
    float fA=sigm(ga[64+lane]), fB=sigm(gc[64+lane]);
    float gA=tanhx(ga[128+lane]), gB=tanhx(gc[128+lane]);
    float oA=sigm(ga[192+lane]),  oB=sigm(gc[192+lane]);
    cA = fA*cA + iA*gA;
    cB = fB*cB + iB*gB;
    H1s[wt  ][lane] = (__bf16)(oA*tanhx(cA));
    H1s[wt+4][lane] = (__bf16)(oB*tanhx(cB));
  };

  __syncthreads();                 // zero-init visible

  // ---- prologue ----
  if (g0){
    f32x4 e0 = MFMA16(cvt8(x0a,x0b), wembf, sp(eb));
    if (quad < 2){
#pragma unroll
      for (int r=0; r<4; ++r) XA[0][quad*4+r][ue] = (__bf16)e0[r];
    }
  }
  __syncthreads();
  if (g0) GEMM0(-1);               // L0(0) gates + emb(1)
  __syncthreads();
  if (g0) EW0(-1);                 // h0(0) -> parity 0
  __syncthreads();

  // ---- steady encoder: slot I computes L0(I+1) & L1(I); 2 barriers/slot ----
#define SLOT(I)                                              \
  if (g0) GEMM0(I); else { if ((I) > 0) EW1(); }             \
  __syncthreads();                                           \
  if (g0) EW0(I); else GEMM1(I);                             \
  __syncthreads();

  for (int ii=0; ii<255; ++ii){
    SLOT(2*ii)
    SLOT(2*ii+1)
  }
  SLOT(510)
#undef SLOT

  // ---- epilogue: L1(511) ----
  if (!g0) EW1();                  // h1(510)
  __syncthreads();
  if (!g0) GEMM1(511);             // reads h0(511) par1, h1(510)
  __syncthreads();
  if (!g0) EW1();                  // h1(511)
  __syncthreads();

  // ================= decoder =================
  // init: XA[0] = [input=h1(511) | h0(511) (from par1)]; H1s = h1(511); c = 0
  for (int idx = tid; idx < 8*128; idx += 512){
    int r = idx >> 7, cc = idx & 127;
    XA[0][r][cc] = (cc < 64) ? H1s[r][cc] : XA[1][r][cc];
  }
  // decoder weights: wave w covers gate cols [32*w, 32*w+31], both layers
#pragma unroll
  for (int l=0; l<2; ++l)
#pragma unroll
    for (int ti=0; ti<2; ++ti){
      const int n = 32*w + 16*ti + col;
      gb[l*2+ti] = dbih[l*256+n] + dbhh[l*256+n];
#pragma unroll
      for (int ks=0; ks<4; ++ks){
        const float* srcw = (ks < 2) ? dWih : dWhh;
        wf[(l*2+ti)*4+ks] = ld8(srcw + ((size_t)(l*256+n))*64 + (ks&1)*32 + quad*8);
      }
    }
  float cD0 = 0.f, cD1 = 0.f;
  __syncthreads();

  auto Ystore = [&](const int t){
    f32x4 ya = sp(rb);
    bf16x8 y0 = *(const bf16x8*)&H1s[row8][quad*8];
    bf16x8 y1 = *(const bf16x8*)&H1s[row8][32 + quad*8];
    ya = MFMA16(y0, wr[0], ya);
    ya = MFMA16(y1, wr[1], ya);
    if (quad < 2 && col < 8){
#pragma unroll
      for (int r=0; r<4; ++r)
        out[((size_t)(b0 + quad*4 + r)*48 + t)*8 + col] = ya[r];
    }
  };

  for (int t=0; t<48; ++t){
    { // P1: GEMM-L0 = [input | h0]  (+ y(t-1) store by wave 0)
      bf16x8 ax0 = *(const bf16x8*)&XA[0][row8][ 0 + quad*8];
      bf16x8 ax1 = *(const bf16x8*)&XA[0][row8][32 + quad*8];
      bf16x8 ah0 = *(const bf16x8*)&XA[0][row8][64 + quad*8];
      bf16x8 ah1 = *(const bf16x8*)&XA[0][row8][96 + quad*8];
      f32x4 B0 = sp(gb[0]), B1 = sp(gb[1]);
      B0=MFMA16(ax0,wf[0],B0); B1=MFMA16(ax0,wf[4],B1);
      B0=MFMA16(ax1,wf[1],B0); B1=MFMA16(ax1,wf[5],B1);
      B0=MFMA16(ah0,wf[2],B0); B1=MFMA16(ah0,wf[6],B1);
      B0=MFMA16(ah1,wf[3],B0); B1=MFMA16(ah1,wf[7],B1);
      f32x4 t0 = (quad&2) ? B1 : B0;
      const int rb2 = (quad&1)*4, nn = 32*w + ((quad&2)?16:0) + col;
#pragma unroll
      for (int r=0; r<4; ++r) Gm[0][rb2+r][nn] = t0[r];
      if (t && w == 0) Ystore(t-1);
    }
    __syncthreads();
    { // P2: EW-L0 (cell = row w, unit lane)
      const float* g = Gm[0][w];
      float i0=sigm(g[lane]), f0=sigm(g[64+lane]);
      float gg=tanhx(g[128+lane]), o0=sigm(g[192+lane]);
      cD0 = f0*cD0 + i0*gg;
      XA[0][w][64+lane] = (__bf16)(o0*tanhx(cD0));
    }
    __syncthreads();
    { // P3: GEMM-L1 = [h0 | h1]
      bf16x8 ah0 = *(const bf16x8*)&XA[0][row8][64 + quad*8];
      bf16x8 ah1 = *(const bf16x8*)&XA[0][row8][96 + quad*8];
      bf16x8 ag0 = *(const bf16x8*)&H1s[row8][quad*8];
      bf16x8 ag1 = *(const bf16x8*)&H1s[row8][32 + quad*8];
      f32x4 B0 = sp(gb[2]), B1 = sp(gb[3]);
      B0=MFMA16(ah0,wf[8],B0);  B1=MFMA16(ah0,wf[12],B1);
      B0=MFMA16(ah1,wf[9],B0);  B1=MFMA16(ah1,wf[13],B1);
      B0=MFMA16(ag0,wf[10],B0); B1=MFMA16(ag0,wf[14],B1);
      B0=MFMA16(ag1,wf[11],B0); B1=MFMA16(ag1,wf[15],B1);
      f32x4 t0 = (quad&2) ? B1 : B0;
      const int rb2 = (quad&1)*4, nn = 32*w + ((quad&2)?16:0) + col;
#pragma unroll
      for (int r=0; r<4; ++r) Gm[1][rb2+r][nn] = t0[r];
    }
    __syncthreads();
    { // P4: EW-L1 -> h1 + feedback input
      const float* g = Gm[1][w];
      float i1=sigm(g[lane]), f1=sigm(g[64+lane]);
      float gg=tanhx(g[128+lane]), o1=sigm(g[192+lane]);
      cD1 = f1*cD1 + i1*gg;
      __bf16 hb = (__bf16)(o1*tanhx(cD1));
      H1s[w][lane]  = hb;
      XA[0][w][lane] = hb;
    }
    __syncthreads();
  }
  if (w == 0) Ystore(47);
}

extern "C" void kernel_launch(void* const* d_in, const int* in_sizes, int n_in,
                              void* d_out, int out_size, void* d_ws, size_t ws_size,
                              hipStream_t stream)
{
  (void)in_sizes; (void)n_in; (void)out_size; (void)d_ws; (void)ws_size;
  const float* X    = (const float*)d_in[0];
  const float* Wemb = (const float*)d_in[2];
  const float* bemb = (const float*)d_in[3];
  const float* eWih = (const float*)d_in[4];
  const float* eWhh = (const float*)d_in[5];
  const float* ebih = (const float*)d_in[6];
  const float* ebhh = (const float*)d_in[7];
  const float* dWih = (const float*)d_in[8];
  const float* dWhh = (const float*)d_in[9];
  const float* dbih = (const float*)d_in[10];
  const float* dbhh = (const float*)d_in[11];
  const float* Wreg = (const float*)d_in[12];
  const float* breg = (const float*)d_in[13];
  float* out = (float*)d_out;

  seq2seq_kernel<<<dim3(256), dim3(512), 0, stream>>>(
      X, Wemb, bemb, eWih, eWhh, ebih, ebhh,
      dWih, dWhh, dbih, dbhh, Wreg, breg, out);
}

// Round 8
// 628.449 us; speedup vs baseline: 1.5801x; 1.0368x over previous
//
#include <hip/hip_runtime.h>
#include <hip/hip_bf16.h>

typedef __bf16 bf16x8 __attribute__((ext_vector_type(8)));
typedef float  f32x4  __attribute__((ext_vector_type(4)));

#define MFMA16(a,b,c) __builtin_amdgcn_mfma_f32_16x16x32_bf16((a),(b),(c),0,0,0)

__device__ __forceinline__ bf16x8 cvt8(f32x4 a, f32x4 b){
  bf16x8 r;
  r[0]=(__bf16)a[0]; r[1]=(__bf16)a[1]; r[2]=(__bf16)a[2]; r[3]=(__bf16)a[3];
  r[4]=(__bf16)b[0]; r[5]=(__bf16)b[1]; r[6]=(__bf16)b[2]; r[7]=(__bf16)b[3];
  return r;
}
__device__ __forceinline__ bf16x8 ld8(const float* p){
  return cvt8(*(const f32x4*)p, *(const f32x4*)(p+4));
}
__device__ __forceinline__ float sigm(float x){
  return __builtin_amdgcn_rcpf(1.f + __expf(-x));
}
__device__ __forceinline__ float tanhx(float x){
  return 1.f - 2.f*__builtin_amdgcn_rcpf(1.f + __expf(2.f*x));
}
__device__ __forceinline__ f32x4 sp(float v){ return (f32x4){v,v,v,v}; }

// Layer-split anti-phase co-issue with 16 waves (4/SIMD):
// waves 0-7 own layer0, waves 8-15 own layer1; each wave covers 32 gate cols
// (2 tiles, 32 weight regs) and EWs exactly 1 cell/lane.
extern "C" __global__ void __launch_bounds__(1024, 4)
seq2seq_kernel(const float* __restrict__ X,
               const float* __restrict__ Wemb, const float* __restrict__ bemb,
               const float* __restrict__ eWih, const float* __restrict__ eWhh,
               const float* __restrict__ ebih, const float* __restrict__ ebhh,
               const float* __restrict__ dWih, const float* __restrict__ dWhh,
               const float* __restrict__ dbih, const float* __restrict__ dbhh,
               const float* __restrict__ Wreg, const float* __restrict__ breg,
               float* __restrict__ out)
{
  // XA[parity][row][144]: cols 0-63 = x/input, 64-127 = h0.
  // Strides: XA 144 bf16 = 72 dw, H1s 80 bf16 = 40 dw, Gm 264 dw — all == 8
  // mod 32 -> every access pattern here is <=2-way (free, m136; R3 measured 0).
  __shared__ __align__(16) __bf16 XA[2][8][144];
  __shared__ __align__(16) __bf16 H1s[8][80];
  __shared__ __align__(16) float  Gm[2][8][264];

  const int tid  = (int)threadIdx.x;
  const int w    = tid >> 6;         // 0..15
  const int grp  = w >> 3;           // 0: layer0 group, 1: layer1 group
  const bool g0  = (grp == 0);
  const int wt   = w & 7;            // wave-in-group; EW row = wt
  const int lane = tid & 63;
  const int col  = lane & 15;
  const int quad = lane >> 4;
  const int row8 = col & 7;          // A real row (M=16 mirrors 8 rows)
  const int b0   = (int)blockIdx.x * 8;
  const int brow = b0 + row8;

  for (int i = tid; i < 2*8*144; i += 1024) (&XA[0][0][0])[i] = (__bf16)0.f;
  for (int i = tid; i < 8*80;    i += 1024) (&H1s[0][0])[i]   = (__bf16)0.f;

  // ---- persistent fragments: 2 tiles x 4 ksteps = 32 regs ----
  bf16x8 wf[8];
  float  gb[2];
#pragma unroll
  for (int ti=0; ti<2; ++ti){
    const int n = 32*wt + 16*ti + col;
    gb[ti] = ebih[grp*256+n] + ebhh[grp*256+n];
#pragma unroll
    for (int ks=0; ks<4; ++ks){
      const float* srcw = (ks < 2) ? eWih : eWhh;
      wf[ti*4+ks] = ld8(srcw + ((size_t)(grp*256+n))*64 + (ks&1)*32 + quad*8);
    }
  }

  // emb fragments: only waves 0-3 use them
  const int ue = (w&3)*16 + col;
  bf16x8 wembf;
  float eb = 0.f;
  const float* xb = X + (size_t)brow*512*32 + quad*8;
  f32x4 pa0, pb0, pa1, pb1;
  if (w < 4){
    wembf = ld8(Wemb + ue*32 + quad*8);
    eb = bemb[ue];
    pa1 = *(const f32x4*)(xb+32); pb1 = *(const f32x4*)(xb+36);   // x(1)
    pa0 = *(const f32x4*)(xb+64); pb0 = *(const f32x4*)(xb+68);   // x(2)
  }

  float cC = 0.f;   // grp0: c0 of (row wt, unit lane); grp1: c1

  // grp0: gates of L0(I+1) -> Gm[0]; emb(I+2) -> XA[I&1].x (waves 0-3)
  auto GEMM0 = [&](const int I){
    const int Px = (I+1)&1, Pr = I&1;
    bf16x8 ax0 = *(const bf16x8*)&XA[Px][row8][ 0 + quad*8];
    bf16x8 ax1 = *(const bf16x8*)&XA[Px][row8][32 + quad*8];
    bf16x8 ah0 = *(const bf16x8*)&XA[Pr][row8][64 + quad*8];
    bf16x8 ah1 = *(const bf16x8*)&XA[Pr][row8][96 + quad*8];
    f32x4 A0 = sp(gb[0]), A1 = sp(gb[1]);
    A0=MFMA16(ax0,wf[0],A0); A1=MFMA16(ax0,wf[4],A1);
    A0=MFMA16(ax1,wf[1],A0); A1=MFMA16(ax1,wf[5],A1);
    A0=MFMA16(ah0,wf[2],A0); A1=MFMA16(ah0,wf[6],A1);
    A0=MFMA16(ah1,wf[3],A0); A1=MFMA16(ah1,wf[7],A1);
    if (I < 510 && w < 4){
      const int s = I&1;
      f32x4 xr0 = s ? pa1 : pa0, xr1 = s ? pb1 : pb0;
      f32x4 ea = MFMA16(cvt8(xr0,xr1), wembf, sp(eb));
      int tn = I+4; if (tn > 511) tn = 511;
      f32x4 na = *(const f32x4*)(xb + (size_t)tn*32);
      f32x4 nb = *(const f32x4*)(xb + (size_t)tn*32 + 4);
      if (s){ pa1=na; pb1=nb; } else { pa0=na; pb0=nb; }
      if (quad < 2){
#pragma unroll
        for (int r=0; r<4; ++r) XA[s][quad*4+r][ue] = (__bf16)ea[r];
      }
    }
    f32x4 t0 = (quad&2) ? A1 : A0;
    const int rb2 = (quad&1)*4;
    const int nn  = 32*wt + ((quad&2)?16:0) + col;
#pragma unroll
    for (int r=0; r<4; ++r) Gm[0][rb2+r][nn] = t0[r];
  };

  // grp1: gates of L1(I) = [h0(I) | h1(I-1)] -> Gm[1]
  auto GEMM1 = [&](const int I){
    const int Pr = I&1;
    bf16x8 ah0 = *(const bf16x8*)&XA[Pr][row8][64 + quad*8];
    bf16x8 ah1 = *(const bf16x8*)&XA[Pr][row8][96 + quad*8];
    bf16x8 ag0 = *(const bf16x8*)&H1s[row8][quad*8];
    bf16x8 ag1 = *(const bf16x8*)&H1s[row8][32 + quad*8];
    f32x4 A0 = sp(gb[0]), A1 = sp(gb[1]);
    A0=MFMA16(ah0,wf[0],A0); A1=MFMA16(ah0,wf[4],A1);
    A0=MFMA16(ah1,wf[1],A0); A1=MFMA16(ah1,wf[5],A1);
    A0=MFMA16(ag0,wf[2],A0); A1=MFMA16(ag0,wf[6],A1);
    A0=MFMA16(ag1,wf[3],A0); A1=MFMA16(ag1,wf[7],A1);
    f32x4 t0 = (quad&2) ? A1 : A0;
    const int rb2 = (quad&1)*4;
    const int nn  = 32*wt + ((quad&2)?16:0) + col;
#pragma unroll
    for (int r=0; r<4; ++r) Gm[1][rb2+r][nn] = t0[r];
  };

  // grp0 EW: 1 cell/lane (row wt, unit lane) -> h0(I+1) at parity (I+1)&1
  auto EW0 = [&](const int I){
    const int Pw = (I+1)&1;
    const float* g = Gm[0][wt];
    float i0=sigm(g[lane]),      f0=sigm(g[64+lane]);
    float gg=tanhx(g[128+lane]), o0=sigm(g[192+lane]);
    cC = f0*cC + i0*gg;
    XA[Pw][wt][64+lane] = (__bf16)(o0*tanhx(cC));
  };

  // grp1 EW -> h1 (single buffer)
  auto EW1 = [&](){
    const float* g = Gm[1][wt];
    float i1=sigm(g[lane]),      f1=sigm(g[64+lane]);
    float gg=tanhx(g[128+lane]), o1=sigm(g[192+lane]);
    cC = f1*cC + i1*gg;
    H1s[wt][lane] = (__bf16)(o1*tanhx(cC));
  };

  __syncthreads();                 // zero-init visible

  // ---- prologue ----
  if (w < 4){
    f32x4 x0a = *(const f32x4*)xb, x0b = *(const f32x4*)(xb+4);
    f32x4 e0 = MFMA16(cvt8(x0a,x0b), wembf, sp(eb));
    if (quad < 2){
#pragma unroll
      for (int r=0; r<4; ++r) XA[0][quad*4+r][ue] = (__bf16)e0[r];
    }
  }
  __syncthreads();
  if (g0) GEMM0(-1);               // L0(0) gates + emb(1)
  __syncthreads();
  if (g0) EW0(-1);                 // h0(0) -> parity 0
  __syncthreads();

  // ---- steady encoder: slot I computes L0(I+1) & L1(I); 2 barriers/slot ----
#define SLOT(I)                                              \
  if (g0) GEMM0(I); else { if ((I) > 0) EW1(); }             \
  __syncthreads();                                           \
  if (g0) EW0(I); else GEMM1(I);                             \
  __syncthreads();

  for (int ii=0; ii<255; ++ii){
    SLOT(2*ii)
    SLOT(2*ii+1)
  }
  SLOT(510)
#undef SLOT

  // ---- epilogue: L1(511) ----
  if (!g0) EW1();                  // h1(510)
  __syncthreads();
  if (!g0) GEMM1(511);             // reads h0(511) (par 1), h1(510)
  __syncthreads();
  if (!g0) EW1();                  // h1(511)
  __syncthreads();

  // ================= decoder =================
  // init: XA[0] = [input=h1(511) | h0(511)]; H1s holds h1(511); c = 0
  for (int idx = tid; idx < 8*128; idx += 1024){
    int r = idx >> 7, cc = idx & 127;
    XA[0][r][cc] = (cc < 64) ? H1s[r][cc] : XA[1][r][cc];
  }
  // regression head (loaded late to keep encoder reg pressure low)
  bf16x8 wr0 = ld8(Wreg + (col&7)*64 +  0 + quad*8);
  bf16x8 wr1 = ld8(Wreg + (col&7)*64 + 32 + quad*8);
  const float rb = breg[col&7];
  // decoder weights: wave w covers gate cols [16w,16w+15], tile for BOTH layers
  float gbd[2];
#pragma unroll
  for (int l=0; l<2; ++l){
    const int n = 16*w + col;
    gbd[l] = dbih[l*256+n] + dbhh[l*256+n];
#pragma unroll
    for (int ks=0; ks<4; ++ks){
      const float* srcw = (ks < 2) ? dWih : dWhh;
      wf[l*4+ks] = ld8(srcw + ((size_t)(l*256+n))*64 + (ks&1)*32 + quad*8);
    }
  }
  cC = 0.f;
  __syncthreads();

  auto Ystore = [&](const int t){
    f32x4 ya = sp(rb);
    bf16x8 y0 = *(const bf16x8*)&H1s[row8][quad*8];
    bf16x8 y1 = *(const bf16x8*)&H1s[row8][32 + quad*8];
    ya = MFMA16(y0, wr0, ya);
    ya = MFMA16(y1, wr1, ya);
    if (quad < 2 && col < 8){
#pragma unroll
      for (int r=0; r<4; ++r)
        out[((size_t)(b0 + quad*4 + r)*48 + t)*8 + col] = ya[r];
    }
  };

  for (int t=0; t<48; ++t){
    { // P1: GEMM-L0 = [input | h0], all 16 waves (tile w)
      bf16x8 ax0 = *(const bf16x8*)&XA[0][row8][ 0 + quad*8];
      bf16x8 ax1 = *(const bf16x8*)&XA[0][row8][32 + quad*8];
      bf16x8 ah0 = *(const bf16x8*)&XA[0][row8][64 + quad*8];
      bf16x8 ah1 = *(const bf16x8*)&XA[0][row8][96 + quad*8];
      f32x4 B0 = sp(gbd[0]);
      B0=MFMA16(ax0,wf[0],B0);
      B0=MFMA16(ax1,wf[1],B0);
      B0=MFMA16(ah0,wf[2],B0);
      B0=MFMA16(ah1,wf[3],B0);
      if (quad < 2){
#pragma unroll
        for (int r=0; r<4; ++r) Gm[0][quad*4+r][16*w+col] = B0[r];
      }
      if (t && w == 0) Ystore(t-1);
    }
    __syncthreads();
    if (w < 8){ // P2: EW-L0 (row w)
      const float* g = Gm[0][w];
      float i0=sigm(g[lane]),      f0=sigm(g[64+lane]);
      float gg=tanhx(g[128+lane]), o0=sigm(g[192+lane]);
      cC = f0*cC + i0*gg;
      XA[0][w][64+lane] = (__bf16)(o0*tanhx(cC));
    }
    __syncthreads();
    { // P3: GEMM-L1 = [h0 | h1], all 16 waves (tile w)
      bf16x8 ah0 = *(const bf16x8*)&XA[0][row8][64 + quad*8];
      bf16x8 ah1 = *(const bf16x8*)&XA[0][row8][96 + quad*8];
      bf16x8 ag0 = *(const bf16x8*)&H1s[row8][quad*8];
      bf16x8 ag1 = *(const bf16x8*)&H1s[row8][32 + quad*8];
      f32x4 B1 = sp(gbd[1]);
      B1=MFMA16(ah0,wf[4],B1);
      B1=MFMA16(ah1,wf[5],B1);
      B1=MFMA16(ag0,wf[6],B1);
      B1=MFMA16(ag1,wf[7],B1);
      if (quad < 2){
#pragma unroll
        for (int r=0; r<4; ++r) Gm[1][quad*4+r][16*w+col] = B1[r];
      }
    }
    __syncthreads();
    if (w >= 8){ // P4: EW-L1 (row w-8) -> h1 + feedback input
      const int rw = w - 8;
      const float* g = Gm[1][rw];
      float i1=sigm(g[lane]),      f1=sigm(g[64+lane]);
      float gg=tanhx(g[128+lane]), o1=sigm(g[192+lane]);
      cC = f1*cC + i1*gg;
      __bf16 hb = (__bf16)(o1*tanhx(cC));
      H1s[rw][lane]   = hb;
      XA[0][rw][lane] = hb;
    }
    __syncthreads();
  }
  if (w == 0) Ystore(47);
}

extern "C" void kernel_launch(void* const* d_in, const int* in_sizes, int n_in,
                              void* d_out, int out_size, void* d_ws, size_t ws_size,
                              hipStream_t stream)
{
  (void)in_sizes; (void)n_in; (void)out_size; (void)d_ws; (void)ws_size;
  const float* X    = (const float*)d_in[0];
  const float* Wemb = (const float*)d_in[2];
  const float* bemb = (const float*)d_in[3];
  const float* eWih = (const float*)d_in[4];
  const float* eWhh = (const float*)d_in[5];
  const float* ebih = (const float*)d_in[6];
  const float* ebhh = (const float*)d_in[7];
  const float* dWih = (const float*)d_in[8];
  const float* dWhh = (const float*)d_in[9];
  const float* dbih = (const float*)d_in[10];
  const float* dbhh = (const float*)d_in[11];
  const float* Wreg = (const float*)d_in[12];
  const float* breg = (const float*)d_in[13];
  float* out = (float*)d_out;

  seq2seq_kernel<<<dim3(256), dim3(1024), 0, stream>>>(
      X, Wemb, bemb, eWih, eWhh, ebih, ebhh,
      dWih, dWhh, dbih, dbhh, Wreg, breg, out);
}